// Round 8
// baseline (18906.717 us; speedup 1.0000x reference)
//
#include <hip/hip_runtime.h>
#include <hip/hip_bf16.h>
#include <math.h>

typedef __hip_bfloat16 bf16;

#define BB 512
#define TT 80
#define DD 540
#define HH 6
#define KK 90
#define LL 6
#define HK 540      // H*K
#define N3 1620     // 3*H*K
#define BT 40960    // B*T
#define TD 43200    // T*D

__device__ inline float toF(float x) { return x; }
__device__ inline float toF(bf16 x) { return __bfloat162float(x); }

// xc[bt_local,d] = embed[ids[bt_local],d] + pos[t,d]   (fp32 in, bf16 out)
__global__ void embed_kernel(const int* __restrict__ ids,
                             const float* __restrict__ embed,
                             const float* __restrict__ pos,
                             bf16* __restrict__ xc, int rows) {
    int idx = blockIdx.x * blockDim.x + threadIdx.x;
    int total = rows * DD;
    if (idx >= total) return;
    int d = idx % DD;
    int bt = idx / DD;
    int t = bt % TT;
    int id = ids[bt];
    float v = embed[(size_t)id * DD + d] + pos[t * DD + d];
    xc[idx] = __float2bfloat16(v);
}

// dst[d][n2], n2 = sel*540 + h*90 + k  <-  W{q,k,v}[l][h][d][k]  (fp32 -> bf16)
__global__ void transpose_w(const float* __restrict__ Wq,
                            const float* __restrict__ Wk,
                            const float* __restrict__ Wv,
                            bf16* __restrict__ dst, int l) {
    int idx = blockIdx.x * blockDim.x + threadIdx.x;
    const int total = DD * N3;
    if (idx >= total) return;
    int n2 = idx % N3;
    int d = idx / N3;
    int sel = n2 / HK;
    int n = n2 % HK;
    int h = n / KK, k = n % KK;
    const float* src = (sel == 0) ? Wq : ((sel == 1) ? Wk : Wv);
    dst[idx] = __float2bfloat16(src[(((size_t)l * HH + h) * DD + d) * KK + k]);
}

// C[M,N] = A[M,Kd] * B[Kd,N]  (+bias, relu), fp32 accumulate, bf16 out.
// BM=128, BN=64, BK=16, 256 threads, 8x4 per thread. Row-clamped A loads,
// guarded C stores.
template <typename TA, typename TB>
__global__ __launch_bounds__(256) void gemm_kernel(
    const TA* __restrict__ A, const TB* __restrict__ B,
    bf16* __restrict__ C, const float* __restrict__ bias,
    int M, int N, int Kd, int lda, int ldb, int ldc, int relu)
{
    __shared__ float As[16][132];
    __shared__ float Bs[16][68];
    int tid = threadIdx.x;
    int ty = tid >> 4, tx = tid & 15;
    int row0 = blockIdx.y * 128, col0 = blockIdx.x * 64;
    float acc[8][4];
#pragma unroll
    for (int i = 0; i < 8; ++i)
#pragma unroll
        for (int j = 0; j < 4; ++j) acc[i][j] = 0.f;

    int ar = tid >> 1;            // 0..127
    int akb = (tid & 1) * 8;      // 0 or 8
    int bi = tid * 4;
    int bkk = bi >> 6;            // 0..15
    int bcc = bi & 63;

    for (int k0 = 0; k0 < Kd; k0 += 16) {
        {
            int arow = row0 + ar;
            if (arow >= M) arow = M - 1;
            const TA* ap = A + (size_t)arow * lda + k0 + akb;
#pragma unroll
            for (int j = 0; j < 8; ++j) {
                int kk = akb + j;
                float v = 0.f;
                if (k0 + kk < Kd) v = toF(ap[j]);
                As[kk][ar] = v;
            }
        }
        {
            float vv[4] = {0.f, 0.f, 0.f, 0.f};
            if (k0 + bkk < Kd) {
                const TB* bp = B + (size_t)(k0 + bkk) * ldb + col0 + bcc;
#pragma unroll
                for (int j = 0; j < 4; ++j)
                    if (col0 + bcc + j < N) vv[j] = toF(bp[j]);
            }
#pragma unroll
            for (int j = 0; j < 4; ++j) Bs[bkk][bcc + j] = vv[j];
        }
        __syncthreads();
#pragma unroll
        for (int kk = 0; kk < 16; ++kk) {
            float a[8], b[4];
#pragma unroll
            for (int i = 0; i < 8; ++i) a[i] = As[kk][ty * 8 + i];
#pragma unroll
            for (int j = 0; j < 4; ++j) b[j] = Bs[kk][tx * 4 + j];
#pragma unroll
            for (int i = 0; i < 8; ++i)
#pragma unroll
                for (int j = 0; j < 4; ++j)
                    acc[i][j] += a[i] * b[j];
        }
        __syncthreads();
    }
#pragma unroll
    for (int i = 0; i < 8; ++i) {
        int r = row0 + ty * 8 + i;
        if (r >= M) continue;
#pragma unroll
        for (int j = 0; j < 4; ++j) {
            int c = col0 + tx * 4 + j;
            if (c < N) {
                float v = acc[i][j];
                if (bias) v += bias[c];
                if (relu) v = fmaxf(v, 0.f);
                C[(size_t)r * ldc + c] = __float2bfloat16(v);
            }
        }
    }
}

// One block per (b_local,h). qkv row: [q(0..539) | k(540..1079) | v(1080..1619)]
// S[t][s] = scale * q[t]·k[s]; softmax over t (per column s); O = attn @ v.
__global__ __launch_bounds__(256) void attn_kernel(const bf16* __restrict__ qkv,
                                                   bf16* __restrict__ obuf) {
    __shared__ bf16 qs[TT * KK];
    __shared__ bf16 ks2[TT * KK];
    __shared__ bf16 vs[TT * KK];
    __shared__ bf16 Ss[TT * 82];
    int b = blockIdx.x / HH, h = blockIdx.x % HH;
    int tid = threadIdx.x;
    const bf16* base = qkv + (size_t)b * TT * N3 + h * KK;
    for (int i = tid; i < TT * KK; i += 256) {
        int t = i / KK, k = i % KK;
        const bf16* row = base + (size_t)t * N3 + k;
        qs[i] = row[0];
        ks2[i] = row[HK];
        vs[i] = row[2 * HK];
    }
    __syncthreads();
    const float scale = 0.105409255338946f;  // 90^-0.5
    for (int i = tid; i < TT * TT; i += 256) {
        int t = i / TT, s = i % TT;
        float accv = 0.f;
        const bf16* qr = qs + t * KK;
        const bf16* kr = ks2 + s * KK;
#pragma unroll 6
        for (int j = 0; j < KK; ++j) accv += toF(qr[j]) * toF(kr[j]);
        Ss[t * 82 + s] = __float2bfloat16(accv * scale);
    }
    __syncthreads();
    // softmax over t for each column s (fp32 math, bf16 storage)
    for (int s = tid; s < TT; s += 256) {
        float m = -1e30f;
        for (int t = 0; t < TT; ++t) m = fmaxf(m, toF(Ss[t * 82 + s]));
        float sum = 0.f;
        for (int t = 0; t < TT; ++t) {
            float e = __expf(toF(Ss[t * 82 + s]) - m);
            sum += e;
            Ss[t * 82 + s] = __float2bfloat16(e);
        }
        float inv = 1.f / sum;
        for (int t = 0; t < TT; ++t)
            Ss[t * 82 + s] = __float2bfloat16(toF(Ss[t * 82 + s]) * inv);
    }
    __syncthreads();
    for (int i = tid; i < TT * KK; i += 256) {
        int t = i / KK, k = i % KK;
        float accv = 0.f;
#pragma unroll 8
        for (int s = 0; s < TT; ++s)
            accv += toF(Ss[t * 82 + s]) * toF(vs[s * KK + k]);
        obuf[((size_t)b * TT + t) * DD + h * KK + k] = __float2bfloat16(accv);
    }
}

// x[row] = LN(delta[row] + x[row]) * g + b   (one block per row; g,b fp32)
__global__ __launch_bounds__(256) void add_ln_kernel(const bf16* __restrict__ delta,
                                                     bf16* __restrict__ x,
                                                     const float* __restrict__ g,
                                                     const float* __restrict__ bta) {
    int row = blockIdx.x;
    int tid = threadIdx.x;
    float vals[3];
    float s1 = 0.f, s2 = 0.f;
#pragma unroll
    for (int j = 0; j < 3; ++j) {
        int c = tid + j * 256;
        float v = 0.f;
        if (c < DD) v = toF(delta[(size_t)row * DD + c]) + toF(x[(size_t)row * DD + c]);
        vals[j] = v;
        s1 += v; s2 += v * v;
    }
    __shared__ float red[8];
    for (int o = 32; o > 0; o >>= 1) {
        s1 += __shfl_down(s1, o, 64);
        s2 += __shfl_down(s2, o, 64);
    }
    int lane = tid & 63, w = tid >> 6;
    if (lane == 0) { red[w * 2] = s1; red[w * 2 + 1] = s2; }
    __syncthreads();
    if (tid == 0) {
        float a = 0.f, c2 = 0.f;
        for (int i = 0; i < 4; ++i) { a += red[i * 2]; c2 += red[i * 2 + 1]; }
        red[0] = a; red[1] = c2;
    }
    __syncthreads();
    float mean = red[0] / DD;
    float var = red[1] / DD - mean * mean;
    float rstd = rsqrtf(var + 1e-5f);
#pragma unroll
    for (int j = 0; j < 3; ++j) {
        int c = tid + j * 256;
        if (c < DD) {
            float o = (vals[j] - mean) * rstd * g[c] + bta[c];
            x[(size_t)row * DD + c] = __float2bfloat16(o);
        }
    }
}

// out[b_local] = sum_i xc[b_local*43200+i] * Wc[i] + bc   (fp32 OUTPUT)
__global__ __launch_bounds__(256) void final_kernel(const bf16* __restrict__ xc,
                                                    const float* __restrict__ Wc,
                                                    const float* __restrict__ bc,
                                                    float* __restrict__ out) {
    int b = blockIdx.x;
    int tid = threadIdx.x;
    float s = 0.f;
    for (int i = tid; i < TD; i += 256)
        s += toF(xc[(size_t)b * TD + i]) * Wc[i];
    for (int o = 32; o > 0; o >>= 1) s += __shfl_down(s, o, 64);
    __shared__ float red[4];
    int lane = tid & 63, w = tid >> 6;
    if (lane == 0) red[w] = s;
    __syncthreads();
    if (tid == 0) {
        float tot = red[0] + red[1] + red[2] + red[3] + bc[0];
        out[b] = tot;
    }
}

extern "C" void kernel_launch(void* const* d_in, const int* in_sizes, int n_in,
                              void* d_out, int out_size, void* d_ws, size_t ws_size,
                              hipStream_t stream) {
    const int* ids    = (const int*)d_in[0];
    const float* embed = (const float*)d_in[1];
    const float* pos  = (const float*)d_in[2];
    const float* Wq   = (const float*)d_in[3];
    const float* Wk   = (const float*)d_in[4];
    const float* Wv   = (const float*)d_in[5];
    const float* W1   = (const float*)d_in[6];
    const float* b1   = (const float*)d_in[7];
    const float* W2   = (const float*)d_in[8];
    const float* b2   = (const float*)d_in[9];
    const float* ln1g = (const float*)d_in[10];
    const float* ln1b = (const float*)d_in[11];
    const float* ln2g = (const float*)d_in[12];
    const float* ln2b = (const float*)d_in[13];
    const float* Wc   = (const float*)d_in[14];
    const float* bc   = (const float*)d_in[15];
    float* out = (float*)d_out;   // fp32 output, per reference

    // Chunk-outer / layer-inner. Per-batch-elem scratch: TT*(DD+N3+DD) bf16
    // = 432,000 B. Weights: all-layer wT (10.5 MB) if it fits, else per-layer.
    const size_t wTallB = (size_t)LL * DD * N3 * 2;   // 10,497,600
    const size_t wTl1B  = (size_t)DD * N3 * 2;        //  1,749,600
    const size_t perB   = (size_t)TT * (DD + N3 + DD) * 2;  // 432,000

    int perLayerT = 0;
    int bch = BB;
    while (bch > 1 && wTallB + (size_t)bch * perB > ws_size) bch >>= 1;
    if (wTallB + (size_t)bch * perB > ws_size) {
        perLayerT = 1;
        bch = BB;
        while (bch > 1 && wTl1B + (size_t)bch * perB > ws_size) bch >>= 1;
    }
    int nch = BB / bch;
    int rows = bch * TT;

    char* p = (char*)d_ws;
    bf16* wT = (bf16*)p;   p += perLayerT ? wTl1B : wTallB;
    bf16* xc = (bf16*)p;   p += (size_t)rows * DD * 2;
    bf16* scr = (bf16*)p;  p += (size_t)rows * N3 * 2;
    bf16* dch = (bf16*)p;

    dim3 gq((N3 + 63) / 64, (rows + 127) / 128);
    dim3 gf((HK + 63) / 64, (rows + 127) / 128);
    const int tpGrid = (DD * N3 + 255) / 256;

    if (!perLayerT)
        for (int l = 0; l < LL; ++l)
            transpose_w<<<tpGrid, 256, 0, stream>>>(Wq, Wk, Wv, wT + (size_t)l * DD * N3, l);

    for (int c = 0; c < nch; ++c) {
        embed_kernel<<<(rows * DD + 255) / 256, 256, 0, stream>>>(
            ids + (size_t)c * rows, embed, pos, xc, rows);
        for (int l = 0; l < LL; ++l) {
            bf16* wTl = perLayerT ? wT : wT + (size_t)l * DD * N3;
            if (perLayerT)
                transpose_w<<<tpGrid, 256, 0, stream>>>(Wq, Wk, Wv, wTl, l);
            gemm_kernel<bf16, bf16><<<gq, 256, 0, stream>>>(
                xc, wTl, scr, (const float*)nullptr,
                rows, N3, DD, DD, N3, N3, 0);
            attn_kernel<<<bch * HH, 256, 0, stream>>>(scr, dch);
            add_ln_kernel<<<rows, 256, 0, stream>>>(dch, xc, ln1g + l * DD, ln1b + l * DD);
            gemm_kernel<bf16, float><<<gf, 256, 0, stream>>>(
                xc, W1 + (size_t)l * DD * HK, scr, b1 + l * HK,
                rows, HK, DD, DD, HK, HK, 1);
            gemm_kernel<bf16, float><<<gf, 256, 0, stream>>>(
                scr, W2 + (size_t)l * HK * DD, dch, b2 + l * DD,
                rows, DD, HK, HK, DD, DD, 0);
            add_ln_kernel<<<rows, 256, 0, stream>>>(dch, xc, ln2g + l * DD, ln2b + l * DD);
        }
        final_kernel<<<bch, 256, 0, stream>>>(xc, Wc, bc, out + (size_t)c * bch);
    }
}

// Round 9
// 5269.572 us; speedup vs baseline: 3.5879x; 3.5879x over previous
//
#include <hip/hip_runtime.h>
#include <hip/hip_bf16.h>
#include <math.h>

typedef __hip_bfloat16 bf16;
typedef __bf16 bf16x8 __attribute__((ext_vector_type(8)));
typedef float floatx4 __attribute__((ext_vector_type(4)));

#define BB 512
#define TT 80
#define DD 540
#define HH 6
#define KK 90
#define LL 6
#define HK 540      // H*K
#define N3 1620     // 3*H*K
#define BT 40960    // B*T
#define TD 43200    // T*D
#define KP 544      // K padded (17 * 32)
#define NQ 1664     // qkv N padded (13 * 128)
#define NF 640      // ff N padded (5 * 128)

__device__ inline float toF(bf16 x) { return __bfloat162float(x); }

// ---------------- weight prep (runs every launch; graph-safe) ----------------

// wTt[l][n(NQ)][k(KP)] = W{q|k|v}[l][h][d=k][kk], n = sel*540+h*90+kk; pads 0
__global__ void prep_wqkv(const float* __restrict__ Wq,
                          const float* __restrict__ Wk,
                          const float* __restrict__ Wv,
                          bf16* __restrict__ wTt) {
    int idx = blockIdx.x * blockDim.x + threadIdx.x;
    const int total = LL * NQ * KP;
    if (idx >= total) return;
    int k = idx % KP;
    int n = (idx / KP) % NQ;
    int l = idx / (KP * NQ);
    float v = 0.f;
    if (k < DD && n < N3) {
        int sel = n / HK;
        int nn = n - sel * HK;
        int h = nn / KK, kk = nn - h * KK;
        const float* W = (sel == 0) ? Wq : ((sel == 1) ? Wk : Wv);
        v = W[(((size_t)l * HH + h) * DD + k) * KK + kk];
    }
    wTt[idx] = __float2bfloat16(v);
}

// Wt[l][n(NF)][k(KP)] = W[l][k][n]  (W is [L][540][540]); pads 0
__global__ void prep_wt(const float* __restrict__ W, bf16* __restrict__ Wt) {
    int idx = blockIdx.x * blockDim.x + threadIdx.x;
    const int total = LL * NF * KP;
    if (idx >= total) return;
    int k = idx % KP;
    int n = (idx / KP) % NF;
    int l = idx / (KP * NF);
    float v = 0.f;
    if (k < DD && n < DD)
        v = W[((size_t)l * DD + k) * DD + n];
    Wt[idx] = __float2bfloat16(v);
}

// ---------------- embed: xc[bt][KP], pad cols zeroed ----------------
__global__ void embed_kernel(const int* __restrict__ ids,
                             const float* __restrict__ embed,
                             const float* __restrict__ pos,
                             bf16* __restrict__ xc, int rows) {
    int idx = blockIdx.x * blockDim.x + threadIdx.x;
    int total = rows * KP;
    if (idx >= total) return;
    int d = idx % KP;
    int bt = idx / KP;
    float v = 0.f;
    if (d < DD) {
        int t = bt % TT;
        v = embed[(size_t)ids[bt] * DD + d] + pos[t * DD + d];
    }
    xc[idx] = __float2bfloat16(v);
}

// ---------------- MFMA GEMM: C[M][ldc] = A[M][KP] * Bt[Nld][KP]^T ----------------
// 128x128 tile, 4 waves (2x2), each wave 4x4 mfma_f32_16x16x32_bf16 subtiles.
// K = KP (544) fixed: 17 BK=32 steps, no K guards. M % 128 == 0, Nld % 128 == 0.
// B pad rows are zero, so A pad cols contribute 0. Epilogue: bias+relu, n>=Nreal -> 0.
__global__ __launch_bounds__(256) void mfma_gemm(
    const bf16* __restrict__ A, int lda,
    const bf16* __restrict__ Bt,
    bf16* __restrict__ C, int ldc, int Nreal,
    const float* __restrict__ bias, int relu)
{
    __shared__ bf16 As[128 * 32];
    __shared__ bf16 Bs[128 * 32];
    const int t = threadIdx.x;
    const int lane = t & 63;
    const int wave = t >> 6;
    const int wm = (wave & 1) * 64;
    const int wn = (wave >> 1) * 64;
    const int row0 = blockIdx.y * 128;
    const int col0 = blockIdx.x * 128;
    const int q = lane >> 4, r = lane & 15;

    floatx4 acc[4][4];
#pragma unroll
    for (int i = 0; i < 4; ++i)
#pragma unroll
        for (int j = 0; j < 4; ++j) acc[i][j] = (floatx4){0.f, 0.f, 0.f, 0.f};

    // staging: thread t covers LDS slot (m = t>>2 [+64], kb = t&3); the slot
    // holds the XOR-swizzled global k-group so ds_read_b128 frags are ~conflict-free
    const int sm = t >> 2;
    const int sgo = ((t & 3) ^ ((t >> 3) & 3)) * 8;   // global k-group offset (elems)
    const int slo = (t & 3) * 8;                      // lds slot offset (elems)
    const bf16* Ab = A + (size_t)row0 * lda;
    const bf16* Bb = Bt + (size_t)col0 * KP;
    const int ksw = (q ^ ((r >> 1) & 3)) * 8;         // read-side swizzle

    for (int k0 = 0; k0 < KP; k0 += 32) {
        __builtin_amdgcn_global_load_lds(
            (const __attribute__((address_space(1))) void*)(Ab + (size_t)sm * lda + k0 + sgo),
            (__attribute__((address_space(3))) void*)(As + sm * 32 + slo), 16, 0, 0);
        __builtin_amdgcn_global_load_lds(
            (const __attribute__((address_space(1))) void*)(Ab + (size_t)(64 + sm) * lda + k0 + sgo),
            (__attribute__((address_space(3))) void*)(As + (64 + sm) * 32 + slo), 16, 0, 0);
        __builtin_amdgcn_global_load_lds(
            (const __attribute__((address_space(1))) void*)(Bb + (size_t)sm * KP + k0 + sgo),
            (__attribute__((address_space(3))) void*)(Bs + sm * 32 + slo), 16, 0, 0);
        __builtin_amdgcn_global_load_lds(
            (const __attribute__((address_space(1))) void*)(Bb + (size_t)(64 + sm) * KP + k0 + sgo),
            (__attribute__((address_space(3))) void*)(Bs + (64 + sm) * 32 + slo), 16, 0, 0);
        __syncthreads();

        bf16x8 af[4], bfr[4];
#pragma unroll
        for (int i = 0; i < 4; ++i)
            af[i] = *(const bf16x8*)(As + (wm + i * 16 + r) * 32 + ksw);
#pragma unroll
        for (int j = 0; j < 4; ++j)
            bfr[j] = *(const bf16x8*)(Bs + (wn + j * 16 + r) * 32 + ksw);
#pragma unroll
        for (int i = 0; i < 4; ++i)
#pragma unroll
            for (int j = 0; j < 4; ++j)
                acc[i][j] = __builtin_amdgcn_mfma_f32_16x16x32_bf16(
                    af[i], bfr[j], acc[i][j], 0, 0, 0);
        __syncthreads();
    }

    // epilogue: C/D layout col=lane&15, row=(lane>>4)*4+reg
#pragma unroll
    for (int i = 0; i < 4; ++i) {
        int m0 = row0 + wm + i * 16 + q * 4;
#pragma unroll
        for (int j = 0; j < 4; ++j) {
            int n = col0 + wn + j * 16 + r;
            bool valid = (n < Nreal);
            float bv = (valid && bias) ? bias[n] : 0.f;
#pragma unroll
            for (int reg = 0; reg < 4; ++reg) {
                float v = acc[i][j][reg] + bv;
                if (relu) v = fmaxf(v, 0.f);
                if (!valid) v = 0.f;
                C[(size_t)(m0 + reg) * ldc + n] = __float2bfloat16(v);
            }
        }
    }
}

// ---------------- attention (strides: qkv ld NQ, out ld NF) ----------------
__global__ __launch_bounds__(256) void attn_kernel(const bf16* __restrict__ qkv,
                                                   bf16* __restrict__ obuf) {
    __shared__ bf16 qs[TT * KK];
    __shared__ bf16 ks2[TT * KK];
    __shared__ bf16 vs[TT * KK];
    __shared__ bf16 Ss[TT * 82];
    int b = blockIdx.x / HH, h = blockIdx.x % HH;
    int tid = threadIdx.x;
    const bf16* base = qkv + (size_t)b * TT * NQ + h * KK;
    for (int i = tid; i < TT * KK; i += 256) {
        int t = i / KK, k = i % KK;
        const bf16* row = base + (size_t)t * NQ + k;
        qs[i] = row[0];
        ks2[i] = row[HK];
        vs[i] = row[2 * HK];
    }
    __syncthreads();
    const float scale = 0.105409255338946f;  // 90^-0.5
    for (int i = tid; i < TT * TT; i += 256) {
        int t = i / TT, s = i % TT;
        float accv = 0.f;
        const bf16* qr = qs + t * KK;
        const bf16* kr = ks2 + s * KK;
#pragma unroll 6
        for (int j = 0; j < KK; ++j) accv += toF(qr[j]) * toF(kr[j]);
        Ss[t * 82 + s] = __float2bfloat16(accv * scale);
    }
    __syncthreads();
    for (int s = tid; s < TT; s += 256) {
        float m = -1e30f;
        for (int t = 0; t < TT; ++t) m = fmaxf(m, toF(Ss[t * 82 + s]));
        float sum = 0.f;
        for (int t = 0; t < TT; ++t) {
            float e = __expf(toF(Ss[t * 82 + s]) - m);
            sum += e;
            Ss[t * 82 + s] = __float2bfloat16(e);
        }
        float inv = 1.f / sum;
        for (int t = 0; t < TT; ++t)
            Ss[t * 82 + s] = __float2bfloat16(toF(Ss[t * 82 + s]) * inv);
    }
    __syncthreads();
    for (int i = tid; i < TT * KK; i += 256) {
        int t = i / KK, k = i % KK;
        float accv = 0.f;
#pragma unroll 8
        for (int s = 0; s < TT; ++s)
            accv += toF(Ss[t * 82 + s]) * toF(vs[s * KK + k]);
        obuf[((size_t)b * TT + t) * NF + h * KK + k] = __float2bfloat16(accv);
    }
}

// ---------------- x = LN(delta + x) * g + b  (delta ld NF, x ld KP) ----------------
__global__ __launch_bounds__(256) void add_ln_kernel(const bf16* __restrict__ delta,
                                                     bf16* __restrict__ x,
                                                     const float* __restrict__ g,
                                                     const float* __restrict__ bta) {
    int row = blockIdx.x;
    int tid = threadIdx.x;
    float vals[3];
    float s1 = 0.f, s2 = 0.f;
#pragma unroll
    for (int j = 0; j < 3; ++j) {
        int c = tid + j * 256;
        float v = 0.f;
        if (c < DD) v = toF(delta[(size_t)row * NF + c]) + toF(x[(size_t)row * KP + c]);
        vals[j] = v;
        s1 += v; s2 += v * v;
    }
    __shared__ float red[8];
    for (int o = 32; o > 0; o >>= 1) {
        s1 += __shfl_down(s1, o, 64);
        s2 += __shfl_down(s2, o, 64);
    }
    int lane = tid & 63, w = tid >> 6;
    if (lane == 0) { red[w * 2] = s1; red[w * 2 + 1] = s2; }
    __syncthreads();
    if (tid == 0) {
        float a = 0.f, c2 = 0.f;
        for (int i = 0; i < 4; ++i) { a += red[i * 2]; c2 += red[i * 2 + 1]; }
        red[0] = a; red[1] = c2;
    }
    __syncthreads();
    float mean = red[0] / DD;
    float var = red[1] / DD - mean * mean;
    float rstd = rsqrtf(var + 1e-5f);
#pragma unroll
    for (int j = 0; j < 3; ++j) {
        int c = tid + j * 256;
        if (c < DD) {
            float o = (vals[j] - mean) * rstd * g[c] + bta[c];
            x[(size_t)row * KP + c] = __float2bfloat16(o);
        }
    }
}

// ---------------- out[b] = sum x[b]·Wc + bc  (x ld KP per row; fp32 out) ----------------
__global__ __launch_bounds__(256) void final_kernel(const bf16* __restrict__ xc,
                                                    const float* __restrict__ Wc,
                                                    const float* __restrict__ bc,
                                                    float* __restrict__ out) {
    int b = blockIdx.x;
    int tid = threadIdx.x;
    const bf16* xb = xc + (size_t)b * TT * KP;
    float s = 0.f;
    for (int i = tid; i < TD; i += 256) {
        int t = i / DD, d = i - t * DD;
        s += toF(xb[(size_t)t * KP + d]) * Wc[i];
    }
    for (int o = 32; o > 0; o >>= 1) s += __shfl_down(s, o, 64);
    __shared__ float red[4];
    int lane = tid & 63, w = tid >> 6;
    if (lane == 0) red[w] = s;
    __syncthreads();
    if (tid == 0) out[b] = red[0] + red[1] + red[2] + red[3] + bc[0];
}

extern "C" void kernel_launch(void* const* d_in, const int* in_sizes, int n_in,
                              void* d_out, int out_size, void* d_ws, size_t ws_size,
                              hipStream_t stream) {
    const int* ids    = (const int*)d_in[0];
    const float* embed = (const float*)d_in[1];
    const float* pos  = (const float*)d_in[2];
    const float* Wq   = (const float*)d_in[3];
    const float* Wk   = (const float*)d_in[4];
    const float* Wv   = (const float*)d_in[5];
    const float* W1   = (const float*)d_in[6];
    const float* b1   = (const float*)d_in[7];
    const float* W2   = (const float*)d_in[8];
    const float* b2   = (const float*)d_in[9];
    const float* ln1g = (const float*)d_in[10];
    const float* ln1b = (const float*)d_in[11];
    const float* ln2g = (const float*)d_in[12];
    const float* ln2b = (const float*)d_in[13];
    const float* Wc   = (const float*)d_in[14];
    const float* bc   = (const float*)d_in[15];
    float* out = (float*)d_out;

    // Workspace: weights (19.2 MB) + chunk activations.
    const size_t wqkvB = (size_t)LL * NQ * KP * 2;   // 10,862,592
    const size_t wffB  = (size_t)LL * NF * KP * 2;   //  4,177,920 each
    const size_t fixed = wqkvB + 2 * wffB;
    const size_t perB  = (size_t)TT * 2 * (KP + NQ + NF);  // 455,680

    int bch = BB;
    while (bch > 8 && fixed + (size_t)bch * perB > ws_size) bch >>= 1;
    int nch = BB / bch;
    int rows = bch * TT;   // multiple of 128 for all bch >= 8

    char* p = (char*)d_ws;
    bf16* wTt = (bf16*)p;  p += wqkvB;
    bf16* W1t = (bf16*)p;  p += wffB;
    bf16* W2t = (bf16*)p;  p += wffB;
    bf16* xc  = (bf16*)p;  p += (size_t)rows * KP * 2;
    bf16* scr = (bf16*)p;  p += (size_t)rows * NQ * 2;   // qkv / ff1 out
    bf16* dch = (bf16*)p;                                 // attn out / ff2 out

    prep_wqkv<<<(LL * NQ * KP + 255) / 256, 256, 0, stream>>>(Wq, Wk, Wv, wTt);
    prep_wt<<<(LL * NF * KP + 255) / 256, 256, 0, stream>>>(W1, W1t);
    prep_wt<<<(LL * NF * KP + 255) / 256, 256, 0, stream>>>(W2, W2t);

    dim3 gq(NQ / 128, rows / 128);
    dim3 gf(NF / 128, rows / 128);

    for (int c = 0; c < nch; ++c) {
        embed_kernel<<<(rows * KP + 255) / 256, 256, 0, stream>>>(
            ids + (size_t)c * rows, embed, pos, xc, rows);
        for (int l = 0; l < LL; ++l) {
            mfma_gemm<<<gq, 256, 0, stream>>>(
                xc, KP, wTt + (size_t)l * NQ * KP, scr, NQ, N3,
                (const float*)nullptr, 0);
            attn_kernel<<<bch * HH, 256, 0, stream>>>(scr, dch);
            add_ln_kernel<<<rows, 256, 0, stream>>>(dch, xc, ln1g + l * DD, ln1b + l * DD);
            mfma_gemm<<<gf, 256, 0, stream>>>(
                xc, KP, W1t + (size_t)l * NF * KP, scr, NF, HK,
                b1 + (size_t)l * HK, 1);
            mfma_gemm<<<gf, 256, 0, stream>>>(
                scr, NF, W2t + (size_t)l * NF * KP, dch, NF, DD,
                b2 + (size_t)l * DD, 0);
            add_ln_kernel<<<rows, 256, 0, stream>>>(dch, xc, ln2g + l * DD, ln2b + l * DD);
        }
        final_kernel<<<bch, 256, 0, stream>>>(xc, Wc, bc, out + (size_t)c * bch);
    }
}

// Round 10
// 3040.701 us; speedup vs baseline: 6.2179x; 1.7330x over previous
//
#include <hip/hip_runtime.h>
#include <hip/hip_bf16.h>
#include <math.h>

typedef __hip_bfloat16 bf16;
typedef __bf16 bf16x8 __attribute__((ext_vector_type(8)));
typedef float floatx4 __attribute__((ext_vector_type(4)));

#define BB 512
#define TT 80
#define DD 540
#define HH 6
#define KK 90
#define LL 6
#define HK 540      // H*K
#define N3 1620     // 3*H*K
#define BT 40960    // B*T
#define TD 43200    // T*D
#define KP 544      // GEMM K padded (17 * 32)
#define NQ 1664     // qkv N padded (13 * 128)
#define NF 640      // ff N padded (5 * 128)
#define TP 104      // attn LDS row stride (96 + 8 pad)

__device__ inline float toF(bf16 x) { return __bfloat162float(x); }

// ---------------- weight prep (runs every launch; graph-safe) ----------------

__global__ void prep_wqkv(const float* __restrict__ Wq,
                          const float* __restrict__ Wk,
                          const float* __restrict__ Wv,
                          bf16* __restrict__ wTt) {
    int idx = blockIdx.x * blockDim.x + threadIdx.x;
    const int total = LL * NQ * KP;
    if (idx >= total) return;
    int k = idx % KP;
    int n = (idx / KP) % NQ;
    int l = idx / (KP * NQ);
    float v = 0.f;
    if (k < DD && n < N3) {
        int sel = n / HK;
        int nn = n - sel * HK;
        int h = nn / KK, kk = nn - h * KK;
        const float* W = (sel == 0) ? Wq : ((sel == 1) ? Wk : Wv);
        v = W[(((size_t)l * HH + h) * DD + k) * KK + kk];
    }
    wTt[idx] = __float2bfloat16(v);
}

__global__ void prep_wt(const float* __restrict__ W, bf16* __restrict__ Wt) {
    int idx = blockIdx.x * blockDim.x + threadIdx.x;
    const int total = LL * NF * KP;
    if (idx >= total) return;
    int k = idx % KP;
    int n = (idx / KP) % NF;
    int l = idx / (KP * NF);
    float v = 0.f;
    if (k < DD && n < DD)
        v = W[((size_t)l * DD + k) * DD + n];
    Wt[idx] = __float2bfloat16(v);
}

__global__ void embed_kernel(const int* __restrict__ ids,
                             const float* __restrict__ embed,
                             const float* __restrict__ pos,
                             bf16* __restrict__ xc, int rows) {
    int idx = blockIdx.x * blockDim.x + threadIdx.x;
    int total = rows * KP;
    if (idx >= total) return;
    int d = idx % KP;
    int bt = idx / KP;
    float v = 0.f;
    if (d < DD) {
        int t = bt % TT;
        v = embed[(size_t)ids[bt] * DD + d] + pos[t * DD + d];
    }
    xc[idx] = __float2bfloat16(v);
}

// ---------------- MFMA GEMM (unchanged from R9) ----------------
__global__ __launch_bounds__(256) void mfma_gemm(
    const bf16* __restrict__ A, int lda,
    const bf16* __restrict__ Bt,
    bf16* __restrict__ C, int ldc, int Nreal,
    const float* __restrict__ bias, int relu)
{
    __shared__ bf16 As[128 * 32];
    __shared__ bf16 Bs[128 * 32];
    const int t = threadIdx.x;
    const int lane = t & 63;
    const int wave = t >> 6;
    const int wm = (wave & 1) * 64;
    const int wn = (wave >> 1) * 64;
    const int row0 = blockIdx.y * 128;
    const int col0 = blockIdx.x * 128;
    const int q = lane >> 4, r = lane & 15;

    floatx4 acc[4][4];
#pragma unroll
    for (int i = 0; i < 4; ++i)
#pragma unroll
        for (int j = 0; j < 4; ++j) acc[i][j] = (floatx4){0.f, 0.f, 0.f, 0.f};

    const int sm = t >> 2;
    const int sgo = ((t & 3) ^ ((t >> 3) & 3)) * 8;
    const int slo = (t & 3) * 8;
    const bf16* Ab = A + (size_t)row0 * lda;
    const bf16* Bb = Bt + (size_t)col0 * KP;
    const int ksw = (q ^ ((r >> 1) & 3)) * 8;

    for (int k0 = 0; k0 < KP; k0 += 32) {
        __builtin_amdgcn_global_load_lds(
            (const __attribute__((address_space(1))) void*)(Ab + (size_t)sm * lda + k0 + sgo),
            (__attribute__((address_space(3))) void*)(As + sm * 32 + slo), 16, 0, 0);
        __builtin_amdgcn_global_load_lds(
            (const __attribute__((address_space(1))) void*)(Ab + (size_t)(64 + sm) * lda + k0 + sgo),
            (__attribute__((address_space(3))) void*)(As + (64 + sm) * 32 + slo), 16, 0, 0);
        __builtin_amdgcn_global_load_lds(
            (const __attribute__((address_space(1))) void*)(Bb + (size_t)sm * KP + k0 + sgo),
            (__attribute__((address_space(3))) void*)(Bs + sm * 32 + slo), 16, 0, 0);
        __builtin_amdgcn_global_load_lds(
            (const __attribute__((address_space(1))) void*)(Bb + (size_t)(64 + sm) * KP + k0 + sgo),
            (__attribute__((address_space(3))) void*)(Bs + (64 + sm) * 32 + slo), 16, 0, 0);
        __syncthreads();

        bf16x8 af[4], bfr[4];
#pragma unroll
        for (int i = 0; i < 4; ++i)
            af[i] = *(const bf16x8*)(As + (wm + i * 16 + r) * 32 + ksw);
#pragma unroll
        for (int j = 0; j < 4; ++j)
            bfr[j] = *(const bf16x8*)(Bs + (wn + j * 16 + r) * 32 + ksw);
#pragma unroll
        for (int i = 0; i < 4; ++i)
#pragma unroll
            for (int j = 0; j < 4; ++j)
                acc[i][j] = __builtin_amdgcn_mfma_f32_16x16x32_bf16(
                    af[i], bfr[j], acc[i][j], 0, 0, 0);
        __syncthreads();
    }

#pragma unroll
    for (int i = 0; i < 4; ++i) {
        int m0 = row0 + wm + i * 16 + q * 4;
#pragma unroll
        for (int j = 0; j < 4; ++j) {
            int n = col0 + wn + j * 16 + r;
            bool valid = (n < Nreal);
            float bv = (valid && bias) ? bias[n] : 0.f;
#pragma unroll
            for (int reg = 0; reg < 4; ++reg) {
                float v = acc[i][j][reg] + bv;
                if (relu) v = fmaxf(v, 0.f);
                if (!valid) v = 0.f;
                C[(size_t)(m0 + reg) * ldc + n] = __float2bfloat16(v);
            }
        }
    }
}

// ---------------- MFMA attention ----------------
// One block (5 waves, 320 thr) per (b,h). LDS: Qs[80][TP], Ks[80][TP] (→P), Vt[96][TP].
// S = Q·K^T (K-dim 90→96, zero pad); softmax over t per column s (in-register);
// P→LDS; O = P·V (K-dim s 80→96, zero pad).
__global__ __launch_bounds__(320) void attn_mfma(const bf16* __restrict__ qkv,
                                                 bf16* __restrict__ obuf) {
    extern __shared__ bf16 lds[];
    bf16* Qs = lds;                    // 80*TP
    bf16* Ks = lds + 80 * TP;          // 80*TP (becomes P)
    bf16* Vt = lds + 160 * TP;         // 96*TP
    const int b = blockIdx.x / HH, h = blockIdx.x % HH;
    const int tid = threadIdx.x;
    const int lane = tid & 63;
    const int w = tid >> 6;            // wave 0..4
    const int q = lane >> 4, r = lane & 15;
    const bf16* base = qkv + (size_t)b * TT * NQ + h * KK;

    // stage Q, K (k-contiguous, zero pad k>=90); V transposed Vt[kv][s]
    for (int i = tid; i < TT * 12; i += 320) {
        int t = i / 12, kg = i % 12;
        const bf16* qr2 = base + (size_t)t * NQ + kg * 8;
        const bf16* kr2 = qr2 + HK;
        const bf16* vr2 = qr2 + 2 * HK;
        bf16* qd = Qs + t * TP + kg * 8;
        bf16* kd = Ks + t * TP + kg * 8;
#pragma unroll
        for (int j = 0; j < 8; ++j) {
            int k = kg * 8 + j;
            bool ok = (k < KK);
            qd[j] = ok ? qr2[j] : __float2bfloat16(0.f);
            kd[j] = ok ? kr2[j] : __float2bfloat16(0.f);
            Vt[(kg * 8 + j) * TP + t] = ok ? vr2[j] : __float2bfloat16(0.f);
        }
    }
    // zero Vt s-pad [80,96) so PV pad terms are exactly 0
    for (int i = tid; i < 96 * 2; i += 320) {
        int kv = i >> 1, sg = i & 1;
        *(bf16x8*)(Vt + kv * TP + 80 + sg * 8) = (bf16x8)(__bf16)0.0f;
    }
    __syncthreads();

    // S-GEMM: wave w -> columns s in [16w, 16w+16)
    floatx4 acc[5];
#pragma unroll
    for (int i = 0; i < 5; ++i) acc[i] = (floatx4){0.f, 0.f, 0.f, 0.f};
    bf16x8 bf[3];
#pragma unroll
    for (int ks = 0; ks < 3; ++ks)
        bf[ks] = *(const bf16x8*)(Ks + (16 * w + r) * TP + ks * 32 + q * 8);
#pragma unroll
    for (int ti = 0; ti < 5; ++ti) {
#pragma unroll
        for (int ks = 0; ks < 3; ++ks) {
            bf16x8 af = *(const bf16x8*)(Qs + (16 * ti + r) * TP + ks * 32 + q * 8);
            acc[ti] = __builtin_amdgcn_mfma_f32_16x16x32_bf16(af, bf[ks], acc[ti], 0, 0, 0);
        }
    }

    // softmax over t for column s = 16w + r (values: t = 16ti + q*4 + reg)
    const float scale = 0.105409255338946f;  // 90^-0.5
    float m = -1e30f;
#pragma unroll
    for (int ti = 0; ti < 5; ++ti)
#pragma unroll
        for (int reg = 0; reg < 4; ++reg) {
            acc[ti][reg] *= scale;
            m = fmaxf(m, acc[ti][reg]);
        }
    m = fmaxf(m, __shfl_xor(m, 16));
    m = fmaxf(m, __shfl_xor(m, 32));
    float sum = 0.f;
    float e[5][4];
#pragma unroll
    for (int ti = 0; ti < 5; ++ti)
#pragma unroll
        for (int reg = 0; reg < 4; ++reg) {
            e[ti][reg] = __expf(acc[ti][reg] - m);
            sum += e[ti][reg];
        }
    sum += __shfl_xor(sum, 16);
    sum += __shfl_xor(sum, 32);
    float inv = 1.f / sum;

    __syncthreads();   // all Ks reads done before P overwrites it

    // write P (into Ks space), layout P[t][s], plus zero s-pad [80,96)
    bf16* P = Ks;
#pragma unroll
    for (int ti = 0; ti < 5; ++ti)
#pragma unroll
        for (int reg = 0; reg < 4; ++reg)
            P[(16 * ti + q * 4 + reg) * TP + 16 * w + r] =
                __float2bfloat16(e[ti][reg] * inv);
    for (int i = tid; i < TT * 2; i += 320) {
        int t2 = i >> 1, sg = i & 1;
        *(bf16x8*)(P + t2 * TP + 80 + sg * 8) = (bf16x8)(__bf16)0.0f;
    }
    __syncthreads();

    // PV: wave w -> O rows t in [16w, 16w+16); n-tiles over kv (6), k over s (3)
    bf16x8 af2[3];
#pragma unroll
    for (int ks = 0; ks < 3; ++ks)
        af2[ks] = *(const bf16x8*)(P + (16 * w + r) * TP + ks * 32 + q * 8);
    bf16* ob = obuf + ((size_t)b * TT) * NF + h * KK;
#pragma unroll
    for (int nt = 0; nt < 6; ++nt) {
        floatx4 o = (floatx4){0.f, 0.f, 0.f, 0.f};
#pragma unroll
        for (int ks = 0; ks < 3; ++ks) {
            bf16x8 bv = *(const bf16x8*)(Vt + (16 * nt + r) * TP + ks * 32 + q * 8);
            o = __builtin_amdgcn_mfma_f32_16x16x32_bf16(af2[ks], bv, o, 0, 0, 0);
        }
        int kv = 16 * nt + r;
        if (kv < KK) {
#pragma unroll
            for (int reg = 0; reg < 4; ++reg) {
                int t2 = 16 * w + q * 4 + reg;
                ob[(size_t)t2 * NF + kv] = __float2bfloat16(o[reg]);
            }
        }
    }
}

// ---------------- x = LN(delta + x) * g + b  (delta ld NF, x ld KP) ----------------
__global__ __launch_bounds__(256) void add_ln_kernel(const bf16* __restrict__ delta,
                                                     bf16* __restrict__ x,
                                                     const float* __restrict__ g,
                                                     const float* __restrict__ bta) {
    int row = blockIdx.x;
    int tid = threadIdx.x;
    float vals[3];
    float s1 = 0.f, s2 = 0.f;
#pragma unroll
    for (int j = 0; j < 3; ++j) {
        int c = tid + j * 256;
        float v = 0.f;
        if (c < DD) v = toF(delta[(size_t)row * NF + c]) + toF(x[(size_t)row * KP + c]);
        vals[j] = v;
        s1 += v; s2 += v * v;
    }
    __shared__ float red[8];
    for (int o = 32; o > 0; o >>= 1) {
        s1 += __shfl_down(s1, o, 64);
        s2 += __shfl_down(s2, o, 64);
    }
    int lane = tid & 63, w = tid >> 6;
    if (lane == 0) { red[w * 2] = s1; red[w * 2 + 1] = s2; }
    __syncthreads();
    if (tid == 0) {
        float a = 0.f, c2 = 0.f;
        for (int i = 0; i < 4; ++i) { a += red[i * 2]; c2 += red[i * 2 + 1]; }
        red[0] = a; red[1] = c2;
    }
    __syncthreads();
    float mean = red[0] / DD;
    float var = red[1] / DD - mean * mean;
    float rstd = rsqrtf(var + 1e-5f);
#pragma unroll
    for (int j = 0; j < 3; ++j) {
        int c = tid + j * 256;
        if (c < DD) {
            float o = (vals[j] - mean) * rstd * g[c] + bta[c];
            x[(size_t)row * KP + c] = __float2bfloat16(o);
        }
    }
}

__global__ __launch_bounds__(256) void final_kernel(const bf16* __restrict__ xc,
                                                    const float* __restrict__ Wc,
                                                    const float* __restrict__ bc,
                                                    float* __restrict__ out) {
    int b = blockIdx.x;
    int tid = threadIdx.x;
    const bf16* xb = xc + (size_t)b * TT * KP;
    float s = 0.f;
    for (int i = tid; i < TD; i += 256) {
        int t = i / DD, d = i - t * DD;
        s += toF(xb[(size_t)t * KP + d]) * Wc[i];
    }
    for (int o = 32; o > 0; o >>= 1) s += __shfl_down(s, o, 64);
    __shared__ float red[4];
    int lane = tid & 63, w = tid >> 6;
    if (lane == 0) red[w] = s;
    __syncthreads();
    if (tid == 0) out[b] = red[0] + red[1] + red[2] + red[3] + bc[0];
}

extern "C" void kernel_launch(void* const* d_in, const int* in_sizes, int n_in,
                              void* d_out, int out_size, void* d_ws, size_t ws_size,
                              hipStream_t stream) {
    const int* ids    = (const int*)d_in[0];
    const float* embed = (const float*)d_in[1];
    const float* pos  = (const float*)d_in[2];
    const float* Wq   = (const float*)d_in[3];
    const float* Wk   = (const float*)d_in[4];
    const float* Wv   = (const float*)d_in[5];
    const float* W1   = (const float*)d_in[6];
    const float* b1   = (const float*)d_in[7];
    const float* W2   = (const float*)d_in[8];
    const float* b2   = (const float*)d_in[9];
    const float* ln1g = (const float*)d_in[10];
    const float* ln1b = (const float*)d_in[11];
    const float* ln2g = (const float*)d_in[12];
    const float* ln2b = (const float*)d_in[13];
    const float* Wc   = (const float*)d_in[14];
    const float* bc   = (const float*)d_in[15];
    float* out = (float*)d_out;

    const size_t wqkvB = (size_t)LL * NQ * KP * 2;
    const size_t wffB  = (size_t)LL * NF * KP * 2;
    const size_t fixed = wqkvB + 2 * wffB;
    const size_t perB  = (size_t)TT * 2 * (KP + NQ + NF);

    int bch = BB;
    while (bch > 8 && fixed + (size_t)bch * perB > ws_size) bch >>= 1;
    int nch = BB / bch;
    int rows = bch * TT;

    char* p = (char*)d_ws;
    bf16* wTt = (bf16*)p;  p += wqkvB;
    bf16* W1t = (bf16*)p;  p += wffB;
    bf16* W2t = (bf16*)p;  p += wffB;
    bf16* xc  = (bf16*)p;  p += (size_t)rows * KP * 2;
    bf16* scr = (bf16*)p;  p += (size_t)rows * NQ * 2;
    bf16* dch = (bf16*)p;

    prep_wqkv<<<(LL * NQ * KP + 255) / 256, 256, 0, stream>>>(Wq, Wk, Wv, wTt);
    prep_wt<<<(LL * NF * KP + 255) / 256, 256, 0, stream>>>(W1, W1t);
    prep_wt<<<(LL * NF * KP + 255) / 256, 256, 0, stream>>>(W2, W2t);

    dim3 gq(NQ / 128, rows / 128);
    dim3 gf(NF / 128, rows / 128);
    const size_t attn_lds = (size_t)(160 + 96) * TP * 2;   // 53,248 B

    for (int c = 0; c < nch; ++c) {
        embed_kernel<<<(rows * KP + 255) / 256, 256, 0, stream>>>(
            ids + (size_t)c * rows, embed, pos, xc, rows);
        for (int l = 0; l < LL; ++l) {
            mfma_gemm<<<gq, 256, 0, stream>>>(
                xc, KP, wTt + (size_t)l * NQ * KP, scr, NQ, N3,
                (const float*)nullptr, 0);
            attn_mfma<<<bch * HH, 320, attn_lds, stream>>>(scr, dch);
            add_ln_kernel<<<rows, 256, 0, stream>>>(dch, xc, ln1g + l * DD, ln1b + l * DD);
            mfma_gemm<<<gf, 256, 0, stream>>>(
                xc, KP, W1t + (size_t)l * NF * KP, scr, NF, HK,
                b1 + (size_t)l * HK, 1);
            mfma_gemm<<<gf, 256, 0, stream>>>(
                scr, NF, W2t + (size_t)l * NF * KP, dch, NF, DD,
                b2 + (size_t)l * DD, 0);
            add_ln_kernel<<<rows, 256, 0, stream>>>(dch, xc, ln2g + l * DD, ln2b + l * DD);
        }
        final_kernel<<<bch, 256, 0, stream>>>(xc, Wc, bc, out + (size_t)c * bch);
    }
}